// Round 2
// baseline (547.605 us; speedup 1.0000x reference)
//
#include <hip/hip_runtime.h>
#include <stdint.h>

typedef unsigned short u16;
typedef __bf16 bf16x8 __attribute__((ext_vector_type(8)));
typedef float f32x4 __attribute__((ext_vector_type(4)));
typedef short s16x8 __attribute__((ext_vector_type(8)));
typedef short s16x4 __attribute__((ext_vector_type(4)));

__device__ __forceinline__ u16 f2bf(float f) {
  unsigned u = __float_as_uint(f);
  u += 0x7fff + ((u >> 16) & 1);   // RNE
  return (u16)(u >> 16);
}

__device__ __forceinline__ void gld16(const void* g, void* l) {
  __builtin_amdgcn_global_load_lds((const __attribute__((address_space(1))) void*)g,
                                   (__attribute__((address_space(3))) void*)l, 16, 0, 0);
}

// ---------------- casts ----------------
__global__ void cast_f32_bf16(const float* __restrict__ in, u16* __restrict__ out, int n) {
  int stride = gridDim.x * blockDim.x;
  for (int i = blockIdx.x * blockDim.x + threadIdx.x; i * 4 < n; i += stride) {
    f32x4 v = *(const f32x4*)(in + (size_t)i * 4);
    s16x4 o;
#pragma unroll
    for (int j = 0; j < 4; ++j) o[j] = (short)f2bf(v[j]);
    *(s16x4*)(out + (size_t)i * 4) = o;
  }
}

// W_O [hd][m] fp32 -> Wot [m][hd] bf16
__global__ void transpose_cast(const float* __restrict__ in, u16* __restrict__ out, int R, int C) {
  int idx = blockIdx.x * 256 + threadIdx.x;
  if (idx < R * C) {
    int r = idx / C, c = idx - r * C;
    out[(size_t)c * R + r] = f2bf(in[idx]);
  }
}

// ---------------- GEMM: C[M,N] = A[M,K] * B[N,K]^T (bf16 in, fp32 acc) ----------------
// 128x128 tile, BK=64, 4 waves (2x2), each wave 64x64 via 4x4 frags of 16x16x32.
// LDS XOR-swizzle (byte ^= (row&7)<<4) with pre-swizzled global source for global_load_lds.
template<int F32OUT>
__global__ __launch_bounds__(256, 3)
void gemm_bt(const u16* __restrict__ A, const u16* __restrict__ B,
             void* __restrict__ Cv, int M, int N, int K) {
  __shared__ __align__(16) u16 As[128 * 64];
  __shared__ __align__(16) u16 Bs[128 * 64];
  const int tid = threadIdx.x;
  const int lane = tid & 63;
  const int wave = tid >> 6;
  const int wr = wave >> 1, wc = wave & 1;
  const int row0 = blockIdx.y * 128, col0 = blockIdx.x * 128;
  const u16* Ab = A + (size_t)row0 * K;
  const u16* Bb = B + (size_t)col0 * K;
  f32x4 acc[4][4] = {};
  for (int kt = 0; kt < K; kt += 64) {
#pragma unroll
    for (int i = 0; i < 4; ++i) {
      int c = i * 256 + tid;         // 16B chunk id (phys, linear in LDS)
      int o = c << 4;                // phys byte
      int row = o >> 7;              // 128B per row
      int ol = o ^ ((row & 7) << 4); // logical byte (involution)
      int colel = (ol & 127) >> 1;
      int ldsoff = (i * 256 + wave * 64) << 4;  // wave-uniform base
      gld16(Ab + (size_t)row * K + kt + colel, (char*)As + ldsoff);
      gld16(Bb + (size_t)row * K + kt + colel, (char*)Bs + ldsoff);
    }
    __syncthreads();
#pragma unroll
    for (int ks = 0; ks < 2; ++ks) {
      const int kb = ks * 64 + ((lane >> 4) << 4);  // byte offset of this lane's 8 k-elems
      bf16x8 af[4], bfr[4];
#pragma unroll
      for (int m = 0; m < 4; ++m) {
        int r = wr * 64 + m * 16 + (lane & 15);
        int o = ((r << 7) + kb) ^ ((r & 7) << 4);
        af[m] = *(const bf16x8*)((const char*)As + o);
      }
#pragma unroll
      for (int n = 0; n < 4; ++n) {
        int r = wc * 64 + n * 16 + (lane & 15);
        int o = ((r << 7) + kb) ^ ((r & 7) << 4);
        bfr[n] = *(const bf16x8*)((const char*)Bs + o);
      }
#pragma unroll
      for (int m = 0; m < 4; ++m)
#pragma unroll
        for (int n = 0; n < 4; ++n)
          acc[m][n] = __builtin_amdgcn_mfma_f32_16x16x32_bf16(af[m], bfr[n], acc[m][n], 0, 0, 0);
    }
    __syncthreads();
  }
  // epilogue: C/D layout col=lane&15, row=(lane>>4)*4+reg
#pragma unroll
  for (int m = 0; m < 4; ++m) {
#pragma unroll
    for (int r = 0; r < 4; ++r) {
      int row = row0 + wr * 64 + m * 16 + ((lane >> 4) << 2) + r;
      int colb = col0 + wc * 64 + (lane & 15);
#pragma unroll
      for (int n = 0; n < 4; ++n) {
        float v = acc[m][n][r];
        if (F32OUT) ((float*)Cv)[(size_t)row * N + colb + n * 16] = v;
        else        ((u16*)Cv)[(size_t)row * N + colb + n * 16] = f2bf(v);
      }
    }
  }
}

// ---------------- flash attention (causal), Dh=64 ----------------
// grid (S/64, H, B); 4 waves, wave w owns q-rows [q0+16w, q0+16w+16)
// V is pre-transposed globally: VT0[hd][M] (row stride M=8192)
__global__ __launch_bounds__(256, 6)
void attn_fwd(const u16* __restrict__ Qg, const u16* __restrict__ Kg,
              const u16* __restrict__ VTg, u16* __restrict__ Og,
              int S, int H) {
  __shared__ __align__(16) u16 Ks[64 * 64];      // [k][d], XOR-swizzled
  __shared__ __align__(16) u16 Vt[64 * 64];      // [d][k], XOR-swizzled
  __shared__ __align__(16) u16 Ps[4][16 * 64];   // per-wave P [q][k], XOR-swizzled
  const int tid = threadIdx.x, lane = tid & 63, wave = tid >> 6;
  const int qt = gridDim.x - 1 - blockIdx.x;     // longest-work blocks first
  const int h = blockIdx.y, b = blockIdx.z;
  const int q0 = qt * 64;
  const int D = H * 64;
  const int M = 4 * S;                           // rows of VT0^T = 8192
  const int l15 = lane & 15, lg = lane >> 4;

  const int qrow = q0 + wave * 16 + l15;
  const u16* qp = Qg + (size_t)(b * S + qrow) * D + h * 64 + (lg << 3);
  bf16x8 qf0 = *(const bf16x8*)qp;
  bf16x8 qf1 = *(const bf16x8*)(qp + 32);

  f32x4 accO[4] = {};
  float mrow[4], lrow[4];
#pragma unroll
  for (int r = 0; r < 4; ++r) { mrow[r] = -__builtin_inff(); lrow[r] = 0.f; }

  for (int kt = 0; kt <= qt; ++kt) {
    const int k0 = kt * 64;
    // stage K tile (64x64, [k][d]) and V^T tile (64x64, [d][k]) swizzled via global_load_lds
#pragma unroll
    for (int i = 0; i < 2; ++i) {
      int c = i * 256 + tid;
      int o = c << 4;
      int row = o >> 7;
      int ol = o ^ ((row & 7) << 4);
      int colel = (ol & 127) >> 1;
      gld16(Kg + (size_t)(b * S + k0 + row) * D + h * 64 + colel,
            (char*)Ks + i * 4096 + wave * 1024);
      gld16(VTg + (size_t)(h * 64 + row) * M + b * S + k0 + colel,
            (char*)Vt + i * 4096 + wave * 1024);
    }
    __syncthreads();

    // S = Q K^T (16 q-rows x 64 k), fp32
    f32x4 sf[4] = {};
#pragma unroll
    for (int dstep = 0; dstep < 2; ++dstep) {
      const int kb = dstep * 64 + (lg << 4);
      bf16x8 qa = dstep ? qf1 : qf0;
#pragma unroll
      for (int kf = 0; kf < 4; ++kf) {
        int r = kf * 16 + l15;
        int o = ((r << 7) + kb) ^ ((r & 7) << 4);
        bf16x8 kb8 = *(const bf16x8*)((const char*)Ks + o);
        sf[kf] = __builtin_amdgcn_mfma_f32_16x16x32_bf16(qa, kb8, sf[kf], 0, 0, 0);
      }
    }

    // scale + causal mask + online softmax (C-layout: row=(lg<<2)+r, col=kf*16+l15)
    float rmax[4];
#pragma unroll
    for (int r = 0; r < 4; ++r) rmax[r] = -__builtin_inff();
    const int qbase = q0 + wave * 16 + (lg << 2);
    const bool diag = (kt == qt);
#pragma unroll
    for (int kf = 0; kf < 4; ++kf) {
      int kcol = k0 + kf * 16 + l15;
#pragma unroll
      for (int r = 0; r < 4; ++r) {
        float s = sf[kf][r] * 0.125f;
        if (diag && kcol > qbase + r) s = -__builtin_inff();
        sf[kf][r] = s;
        rmax[r] = fmaxf(rmax[r], s);
      }
    }
#pragma unroll
    for (int off = 1; off < 16; off <<= 1)
#pragma unroll
      for (int r = 0; r < 4; ++r)
        rmax[r] = fmaxf(rmax[r], __shfl_xor(rmax[r], off, 64));
    float fr[4], psum[4];
#pragma unroll
    for (int r = 0; r < 4; ++r) {
      float mnew = fmaxf(mrow[r], rmax[r]);
      fr[r] = __expf(mrow[r] - mnew);   // 0 on first tile (mrow=-inf, mnew finite)
      mrow[r] = mnew;
      lrow[r] *= fr[r];
      psum[r] = 0.f;
    }
#pragma unroll
    for (int kf = 0; kf < 4; ++kf) {
#pragma unroll
      for (int r = 0; r < 4; ++r) {
        float p = __expf(sf[kf][r] - mrow[r]);
        psum[r] += p;
        int prow = (lg << 2) + r;
        int pcol = kf * 16 + l15;
        int ob = ((prow << 7) + (pcol << 1)) ^ ((prow & 7) << 4);
        *(u16*)((char*)&Ps[wave][0] + ob) = f2bf(p);
      }
    }
#pragma unroll
    for (int off = 1; off < 16; off <<= 1)
#pragma unroll
      for (int r = 0; r < 4; ++r)
        psum[r] += __shfl_xor(psum[r], off, 64);
#pragma unroll
    for (int r = 0; r < 4; ++r) lrow[r] += psum[r];
#pragma unroll
    for (int df = 0; df < 4; ++df)
#pragma unroll
      for (int r = 0; r < 4; ++r) accO[df][r] *= fr[r];

    // O += P V   (P per-wave in LDS; same-wave ds_write->ds_read, no barrier needed)
#pragma unroll
    for (int ks = 0; ks < 2; ++ks) {
      const int kb = ks * 64 + (lg << 4);
      int po = ((l15 << 7) + kb) ^ ((l15 & 7) << 4);
      bf16x8 pa = *(const bf16x8*)((const char*)&Ps[wave][0] + po);
#pragma unroll
      for (int df = 0; df < 4; ++df) {
        int vr = df * 16 + l15;
        int vo = ((vr << 7) + kb) ^ ((vr & 7) << 4);
        bf16x8 vb8 = *(const bf16x8*)((const char*)Vt + vo);
        accO[df] = __builtin_amdgcn_mfma_f32_16x16x32_bf16(pa, vb8, accO[df], 0, 0, 0);
      }
    }
    __syncthreads();  // protect Ks/Vt before next-tile staging
  }

  // write attn_out [b*S+q][h*64+d] bf16
#pragma unroll
  for (int df = 0; df < 4; ++df) {
#pragma unroll
    for (int r = 0; r < 4; ++r) {
      int row = q0 + wave * 16 + (lg << 2) + r;
      int col = h * 64 + df * 16 + l15;
      Og[(size_t)(b * S + row) * D + col] = f2bf(accO[df][r] / lrow[r]);
    }
  }
}

// ---------------- launch ----------------
extern "C" void kernel_launch(void* const* d_in, const int* in_sizes, int n_in,
                              void* d_out, int out_size, void* d_ws, size_t ws_size,
                              hipStream_t stream) {
  const float* residual = (const float*)d_in[0];
  const float* W_Q = (const float*)d_in[1];
  const float* W_K = (const float*)d_in[2];
  const float* W_V = (const float*)d_in[3];
  const float* W_O = (const float*)d_in[4];
  float* out = (float*)d_out;
  const int B = 4, S = 2048, D = 1024, H = 16;
  const int M = B * S;  // 8192

  char* ws = (char*)d_ws;
  size_t off = 0;
  auto alloc = [&](size_t elems) {
    u16* p = (u16*)(ws + off);
    off += ((elems * 2 + 255) & ~(size_t)255);
    return p;
  };
  u16* resb = alloc((size_t)M * D);
  u16* Wqb  = alloc((size_t)D * D);
  u16* Wkb  = alloc((size_t)D * D);
  u16* Wvb  = alloc((size_t)D * D);
  u16* Wot  = alloc((size_t)D * D);
  u16* Qw   = alloc((size_t)M * D);
  u16* Kw   = alloc((size_t)M * D);
  u16* VT0  = alloc((size_t)M * D);   // V^T: [hd][b*S+s], row stride M
  u16* AOw  = resb;  // residual-bf16 is dead after the QKV GEMMs — alias

  cast_f32_bf16<<<1024, 256, 0, stream>>>(residual, resb, M * D);
  cast_f32_bf16<<<256, 256, 0, stream>>>(W_Q, Wqb, D * D);
  cast_f32_bf16<<<256, 256, 0, stream>>>(W_K, Wkb, D * D);
  cast_f32_bf16<<<256, 256, 0, stream>>>(W_V, Wvb, D * D);
  transpose_cast<<<(D * D + 255) / 256, 256, 0, stream>>>(W_O, Wot, D, D);

  dim3 g(D / 128, M / 128);  // (8, 64)
  gemm_bt<0><<<g, 256, 0, stream>>>(resb, Wqb, Qw, M, D, D);
  gemm_bt<0><<<g, 256, 0, stream>>>(resb, Wkb, Kw, M, D, D);
  // V^T directly: VT0[hd][bs] = sum_m W_V[hd][m] * res[bs][m]  (swapped operands, same cost)
  dim3 gv(M / 128, D / 128);  // (64, 8)
  gemm_bt<0><<<gv, 256, 0, stream>>>(Wvb, resb, VT0, D, M, D);

  attn_fwd<<<dim3(S / 64, H, B), 256, 0, stream>>>(Qw, Kw, VT0, AOw, S, H);

  gemm_bt<1><<<g, 256, 0, stream>>>(AOw, Wot, out, M, D, D);
}

// Round 3
// 383.938 us; speedup vs baseline: 1.4263x; 1.4263x over previous
//
#include <hip/hip_runtime.h>
#include <stdint.h>

typedef unsigned short u16;
typedef __bf16 bf16x8 __attribute__((ext_vector_type(8)));
typedef float f32x4 __attribute__((ext_vector_type(4)));
typedef short s16x8 __attribute__((ext_vector_type(8)));
typedef short s16x4 __attribute__((ext_vector_type(4)));

__device__ __forceinline__ u16 f2bf(float f) {
  unsigned u = __float_as_uint(f);
  u += 0x7fff + ((u >> 16) & 1);   // RNE
  return (u16)(u >> 16);
}

__device__ __forceinline__ void gld16(const void* g, void* l) {
  __builtin_amdgcn_global_load_lds((const __attribute__((address_space(1))) void*)g,
                                   (__attribute__((address_space(3))) void*)l, 16, 0, 0);
}

// ---------------- casts ----------------
__global__ void cast_f32_bf16(const float* __restrict__ in, u16* __restrict__ out, int n) {
  int stride = gridDim.x * blockDim.x;
  for (int i = blockIdx.x * blockDim.x + threadIdx.x; i * 4 < n; i += stride) {
    f32x4 v = *(const f32x4*)(in + (size_t)i * 4);
    s16x4 o;
#pragma unroll
    for (int j = 0; j < 4; ++j) o[j] = (short)f2bf(v[j]);
    *(s16x4*)(out + (size_t)i * 4) = o;
  }
}

// W_O [hd][m] fp32 -> Wot [m][hd] bf16
__global__ void transpose_cast(const float* __restrict__ in, u16* __restrict__ out, int R, int C) {
  int idx = blockIdx.x * 256 + threadIdx.x;
  if (idx < R * C) {
    int r = idx / C, c = idx - r * C;
    out[(size_t)c * R + r] = f2bf(in[idx]);
  }
}

// ---------------- GEMM: C[M,N] = A[M,K] * B[N,K]^T (bf16 in, fp32 acc) ----------------
template<int F32OUT>
__global__ __launch_bounds__(256, 3)
void gemm_bt(const u16* __restrict__ A, const u16* __restrict__ B,
             void* __restrict__ Cv, int M, int N, int K, int LDC) {
  __shared__ __align__(16) u16 As[128 * 64];
  __shared__ __align__(16) u16 Bs[128 * 64];
  const int tid = threadIdx.x;
  const int lane = tid & 63;
  const int wave = tid >> 6;
  const int wr = wave >> 1, wc = wave & 1;
  const int row0 = blockIdx.y * 128, col0 = blockIdx.x * 128;
  const u16* Ab = A + (size_t)row0 * K;
  const u16* Bb = B + (size_t)col0 * K;
  f32x4 acc[4][4] = {};
  for (int kt = 0; kt < K; kt += 64) {
#pragma unroll
    for (int i = 0; i < 4; ++i) {
      int c = i * 256 + tid;
      int o = c << 4;
      int row = o >> 7;
      int ol = o ^ ((row & 7) << 4);
      int colel = (ol & 127) >> 1;
      int ldsoff = (i * 256 + wave * 64) << 4;
      gld16(Ab + (size_t)row * K + kt + colel, (char*)As + ldsoff);
      gld16(Bb + (size_t)row * K + kt + colel, (char*)Bs + ldsoff);
    }
    __syncthreads();
#pragma unroll
    for (int ks = 0; ks < 2; ++ks) {
      const int kb = ks * 64 + ((lane >> 4) << 4);
      bf16x8 af[4], bfr[4];
#pragma unroll
      for (int m = 0; m < 4; ++m) {
        int r = wr * 64 + m * 16 + (lane & 15);
        int o = ((r << 7) + kb) ^ ((r & 7) << 4);
        af[m] = *(const bf16x8*)((const char*)As + o);
      }
#pragma unroll
      for (int n = 0; n < 4; ++n) {
        int r = wc * 64 + n * 16 + (lane & 15);
        int o = ((r << 7) + kb) ^ ((r & 7) << 4);
        bfr[n] = *(const bf16x8*)((const char*)Bs + o);
      }
#pragma unroll
      for (int m = 0; m < 4; ++m)
#pragma unroll
        for (int n = 0; n < 4; ++n)
          acc[m][n] = __builtin_amdgcn_mfma_f32_16x16x32_bf16(af[m], bfr[n], acc[m][n], 0, 0, 0);
    }
    __syncthreads();
  }
#pragma unroll
  for (int m = 0; m < 4; ++m) {
#pragma unroll
    for (int r = 0; r < 4; ++r) {
      int row = row0 + wr * 64 + m * 16 + ((lane >> 4) << 2) + r;
      int colb = col0 + wc * 64 + (lane & 15);
#pragma unroll
      for (int n = 0; n < 4; ++n) {
        float v = acc[m][n][r];
        if (F32OUT) ((float*)Cv)[(size_t)row * LDC + colb + n * 16] = v;
        else        ((u16*)Cv)[(size_t)row * LDC + colb + n * 16] = f2bf(v);
      }
    }
  }
}

// ---------------- flash attention (causal), Dh=64, QBLK=128 ----------------
// Flat grid of 1024 blocks; XCD-aware decode groups all 16 q-strips of an
// (h,b) pair onto one XCD (KV slice ~0.5MB -> L2-resident), longest first.
// 4 waves; wave w owns q-rows [q0+32w, q0+32w+32) as 2 frags of 16.
// K/V double-buffered in LDS; prefetch tile kt+1 before computing kt.
__global__ __launch_bounds__(256, 3)
void attn_fwd(const u16* __restrict__ Qg, const u16* __restrict__ Kg,
              const u16* __restrict__ VTg, u16* __restrict__ Og,
              int S, int H, int LDV) {
  __shared__ __align__(16) u16 Kb[2][64 * 64];   // [k][d], XOR-swizzled
  __shared__ __align__(16) u16 Vb[2][64 * 64];   // [d][k], XOR-swizzled
  __shared__ __align__(16) u16 Ps[4][16 * 64];   // per-wave P frag, XOR-swizzled
  const int tid = threadIdx.x, lane = tid & 63, wave = tid >> 6;
  const int lin = blockIdx.x;
  const int xcd = lin & 7, slot = lin >> 3;
  const int pair = xcd * 8 + (slot >> 4);        // 64 (h,b) pairs, 8 per XCD
  const int strip = slot & 15;
  const int h = pair & 15, b = pair >> 4;
  const int qt = 15 - strip;                     // longest-work strips first
  const int q0 = qt * 128;
  const int D = H * 64;
  const int l15 = lane & 15, lg = lane >> 4;
  const int wq0 = q0 + wave * 32;

  // Q fragments: qf[frag][dstep]
  bf16x8 qf[2][2];
#pragma unroll
  for (int f = 0; f < 2; ++f) {
    const u16* qp = Qg + (size_t)(b * S + wq0 + f * 16 + l15) * D + h * 64 + (lg << 3);
    qf[f][0] = *(const bf16x8*)qp;
    qf[f][1] = *(const bf16x8*)(qp + 32);
  }

  f32x4 accO[2][4] = {};
  float mrow[2][4], lrow[2][4];
#pragma unroll
  for (int f = 0; f < 2; ++f)
#pragma unroll
    for (int r = 0; r < 4; ++r) { mrow[f][r] = -__builtin_inff(); lrow[f][r] = 0.f; }

  const int nkt = 2 * qt + 2;

  auto STAGE = [&](int kt, int bufi) {
    const int k0 = kt * 64;
#pragma unroll
    for (int i = 0; i < 2; ++i) {
      int c = i * 256 + tid;
      int o = c << 4;
      int row = o >> 7;
      int ol = o ^ ((row & 7) << 4);
      int colel = (ol & 127) >> 1;
      int ldsoff = i * 4096 + wave * 1024;
      gld16(Kg + (size_t)(b * S + k0 + row) * D + h * 64 + colel,
            (char*)&Kb[bufi][0] + ldsoff);
      gld16(VTg + (size_t)(h * 64 + row) * LDV + b * S + k0 + colel,
            (char*)&Vb[bufi][0] + ldsoff);
    }
  };

  STAGE(0, 0);
  __syncthreads();

  for (int kt = 0; kt < nkt; ++kt) {
    const int cur = kt & 1;
    if (kt + 1 < nkt) STAGE(kt + 1, cur ^ 1);

    const int k0 = kt * 64;
    if (k0 <= wq0 + 31) {                        // wave has any unmasked col
      // ---- QK^T: sf[frag][kf], K frags shared across the two q-frags
      f32x4 sf[2][4] = {};
#pragma unroll
      for (int dstep = 0; dstep < 2; ++dstep) {
        const int kb = dstep * 64 + (lg << 4);
#pragma unroll
        for (int kf = 0; kf < 4; ++kf) {
          int r = kf * 16 + l15;
          int o = ((r << 7) + kb) ^ ((r & 7) << 4);
          bf16x8 k8 = *(const bf16x8*)((const char*)&Kb[cur][0] + o);
          sf[0][kf] = __builtin_amdgcn_mfma_f32_16x16x32_bf16(qf[0][dstep], k8, sf[0][kf], 0, 0, 0);
          sf[1][kf] = __builtin_amdgcn_mfma_f32_16x16x32_bf16(qf[1][dstep], k8, sf[1][kf], 0, 0, 0);
        }
      }

      const bool needmask = (k0 + 63 > wq0);
#pragma unroll
      for (int f = 0; f < 2; ++f) {
        // scale + causal mask + row max
        float rmax[4];
#pragma unroll
        for (int r = 0; r < 4; ++r) rmax[r] = -__builtin_inff();
        const int qbase = wq0 + f * 16 + (lg << 2);
#pragma unroll
        for (int kf = 0; kf < 4; ++kf) {
          int kcol = k0 + kf * 16 + l15;
#pragma unroll
          for (int r = 0; r < 4; ++r) {
            float s = sf[f][kf][r] * 0.125f;
            if (needmask && kcol > qbase + r) s = -__builtin_inff();
            sf[f][kf][r] = s;
            rmax[r] = fmaxf(rmax[r], s);
          }
        }
#pragma unroll
        for (int off = 1; off < 16; off <<= 1)
#pragma unroll
          for (int r = 0; r < 4; ++r)
            rmax[r] = fmaxf(rmax[r], __shfl_xor(rmax[r], off, 64));
        float scl[4], psum[4];
#pragma unroll
        for (int r = 0; r < 4; ++r) {
          float mnew = fmaxf(mrow[f][r], rmax[r]);
          scl[r] = __expf(mrow[f][r] - mnew);
          mrow[f][r] = mnew;
          lrow[f][r] *= scl[r];
          psum[r] = 0.f;
        }
        // P = exp(s - m), store to per-wave LDS frag (swizzled)
#pragma unroll
        for (int kf = 0; kf < 4; ++kf) {
#pragma unroll
          for (int r = 0; r < 4; ++r) {
            float p = __expf(sf[f][kf][r] - mrow[f][r]);
            psum[r] += p;
            int prow = (lg << 2) + r;
            int pcol = kf * 16 + l15;
            int ob = ((prow << 7) + (pcol << 1)) ^ ((prow & 7) << 4);
            *(u16*)((char*)&Ps[wave][0] + ob) = f2bf(p);
          }
        }
#pragma unroll
        for (int off = 1; off < 16; off <<= 1)
#pragma unroll
          for (int r = 0; r < 4; ++r)
            psum[r] += __shfl_xor(psum[r], off, 64);
#pragma unroll
        for (int r = 0; r < 4; ++r) lrow[f][r] += psum[r];
#pragma unroll
        for (int df = 0; df < 4; ++df)
#pragma unroll
          for (int r = 0; r < 4; ++r) accO[f][df][r] *= scl[r];

        // ---- O += P V  (same-wave LDS write->read, in-order)
#pragma unroll
        for (int ks = 0; ks < 2; ++ks) {
          const int kb = ks * 64 + (lg << 4);
          int po = ((l15 << 7) + kb) ^ ((l15 & 7) << 4);
          bf16x8 pa = *(const bf16x8*)((const char*)&Ps[wave][0] + po);
#pragma unroll
          for (int df = 0; df < 4; ++df) {
            int vr = df * 16 + l15;
            int vo = ((vr << 7) + kb) ^ ((vr & 7) << 4);
            bf16x8 v8 = *(const bf16x8*)((const char*)&Vb[cur][0] + vo);
            accO[f][df] = __builtin_amdgcn_mfma_f32_16x16x32_bf16(pa, v8, accO[f][df], 0, 0, 0);
          }
        }
      }
    }
    __syncthreads();   // drains prefetch vmcnt + protects buffers
  }

  // write attn_out [b*S+q][h*64+d] bf16
#pragma unroll
  for (int f = 0; f < 2; ++f) {
#pragma unroll
    for (int df = 0; df < 4; ++df) {
#pragma unroll
      for (int r = 0; r < 4; ++r) {
        int row = wq0 + f * 16 + (lg << 2) + r;
        int col = h * 64 + df * 16 + l15;
        Og[(size_t)(b * S + row) * D + col] = f2bf(accO[f][df][r] / lrow[f][r]);
      }
    }
  }
}

// ---------------- launch ----------------
extern "C" void kernel_launch(void* const* d_in, const int* in_sizes, int n_in,
                              void* d_out, int out_size, void* d_ws, size_t ws_size,
                              hipStream_t stream) {
  const float* residual = (const float*)d_in[0];
  const float* W_Q = (const float*)d_in[1];
  const float* W_K = (const float*)d_in[2];
  const float* W_V = (const float*)d_in[3];
  const float* W_O = (const float*)d_in[4];
  float* out = (float*)d_out;
  const int B = 4, S = 2048, D = 1024, H = 16;
  const int M = B * S;       // 8192
  const int LDV = M + 64;    // 8256: odd multiple of 64 elems (129x128B rows)

  char* ws = (char*)d_ws;
  size_t off = 0;
  auto alloc = [&](size_t elems) {
    u16* p = (u16*)(ws + off);
    off += ((elems * 2 + 255) & ~(size_t)255);
    return p;
  };
  u16* resb = alloc((size_t)M * D);
  u16* Wqb  = alloc((size_t)D * D);
  u16* Wkb  = alloc((size_t)D * D);
  u16* Wvb  = alloc((size_t)D * D);
  u16* Wot  = alloc((size_t)D * D);
  u16* Qw   = alloc((size_t)M * D);
  u16* Kw   = alloc((size_t)M * D);
  u16* VT0  = alloc((size_t)D * LDV);  // V^T: [hd][b*S+s], padded row stride
  u16* AOw  = resb;  // residual-bf16 dead after QKV GEMMs — alias

  cast_f32_bf16<<<1024, 256, 0, stream>>>(residual, resb, M * D);
  cast_f32_bf16<<<256, 256, 0, stream>>>(W_Q, Wqb, D * D);
  cast_f32_bf16<<<256, 256, 0, stream>>>(W_K, Wkb, D * D);
  cast_f32_bf16<<<256, 256, 0, stream>>>(W_V, Wvb, D * D);
  transpose_cast<<<(D * D + 255) / 256, 256, 0, stream>>>(W_O, Wot, D, D);

  dim3 g(D / 128, M / 128);  // (8, 64)
  gemm_bt<0><<<g, 256, 0, stream>>>(resb, Wqb, Qw, M, D, D, D);
  gemm_bt<0><<<g, 256, 0, stream>>>(resb, Wkb, Kw, M, D, D, D);
  // V^T directly: VT0[hd][bs] = sum_m W_V[hd][m] * res[bs][m]
  dim3 gv(M / 128, D / 128);  // (64, 8)
  gemm_bt<0><<<gv, 256, 0, stream>>>(Wvb, resb, VT0, D, M, D, LDV);

  attn_fwd<<<dim3(1024), 256, 0, stream>>>(Qw, Kw, VT0, AOw, S, H, LDV);

  gemm_bt<1><<<g, 256, 0, stream>>>(AOw, Wot, out, M, D, D, D);
}

// Round 6
// 306.633 us; speedup vs baseline: 1.7859x; 1.2521x over previous
//
#include <hip/hip_runtime.h>
#include <stdint.h>

typedef unsigned short u16;
typedef __bf16 bf16x8 __attribute__((ext_vector_type(8)));
typedef float f32x4 __attribute__((ext_vector_type(4)));
typedef short s16x8 __attribute__((ext_vector_type(8)));
typedef short s16x4 __attribute__((ext_vector_type(4)));

__device__ __forceinline__ u16 f2bf(float f) {
  unsigned u = __float_as_uint(f);
  u += 0x7fff + ((u >> 16) & 1);   // RNE
  return (u16)(u >> 16);
}

__device__ __forceinline__ void gld16(const void* g, void* l) {
  __builtin_amdgcn_global_load_lds((const __attribute__((address_space(1))) void*)g,
                                   (__attribute__((address_space(3))) void*)l, 16, 0, 0);
}

// ---------------- casts ----------------
__global__ void cast_f32_bf16(const float* __restrict__ in, u16* __restrict__ out, int n) {
  int stride = gridDim.x * blockDim.x;
  for (int i = blockIdx.x * blockDim.x + threadIdx.x; i * 4 < n; i += stride) {
    f32x4 v = *(const f32x4*)(in + (size_t)i * 4);
    s16x4 o;
#pragma unroll
    for (int j = 0; j < 4; ++j) o[j] = (short)f2bf(v[j]);
    *(s16x4*)(out + (size_t)i * 4) = o;
  }
}

// W_O [hd][m] fp32 -> Wot [m][hd] bf16
__global__ void transpose_cast(const float* __restrict__ in, u16* __restrict__ out, int R, int C) {
  int idx = blockIdx.x * 256 + threadIdx.x;
  if (idx < R * C) {
    int r = idx / C, c = idx - r * C;
    out[(size_t)c * R + r] = f2bf(in[idx]);
  }
}

// ---------------- GEMM: C[M,N] = A[M,K] * B[N,K]^T (bf16 in, fp32 acc) ----------------
template<int F32OUT>
__global__ __launch_bounds__(256, 3)
void gemm_bt(const u16* __restrict__ A, const u16* __restrict__ B,
             void* __restrict__ Cv, int M, int N, int K, int LDC) {
  __shared__ __align__(16) u16 As[128 * 64];
  __shared__ __align__(16) u16 Bs[128 * 64];
  const int tid = threadIdx.x;
  const int lane = tid & 63;
  const int wave = tid >> 6;
  const int wr = wave >> 1, wc = wave & 1;
  const int row0 = blockIdx.y * 128, col0 = blockIdx.x * 128;
  const u16* Ab = A + (size_t)row0 * K;
  const u16* Bb = B + (size_t)col0 * K;
  f32x4 acc[4][4] = {};
  for (int kt = 0; kt < K; kt += 64) {
#pragma unroll
    for (int i = 0; i < 4; ++i) {
      int c = i * 256 + tid;
      int o = c << 4;
      int row = o >> 7;
      int ol = o ^ ((row & 7) << 4);
      int colel = (ol & 127) >> 1;
      int ldsoff = (i * 256 + wave * 64) << 4;
      gld16(Ab + (size_t)row * K + kt + colel, (char*)As + ldsoff);
      gld16(Bb + (size_t)row * K + kt + colel, (char*)Bs + ldsoff);
    }
    __syncthreads();
#pragma unroll
    for (int ks = 0; ks < 2; ++ks) {
      const int kb = ks * 64 + ((lane >> 4) << 4);
      bf16x8 af[4], bfr[4];
#pragma unroll
      for (int m = 0; m < 4; ++m) {
        int r = wr * 64 + m * 16 + (lane & 15);
        int o = ((r << 7) + kb) ^ ((r & 7) << 4);
        af[m] = *(const bf16x8*)((const char*)As + o);
      }
#pragma unroll
      for (int n = 0; n < 4; ++n) {
        int r = wc * 64 + n * 16 + (lane & 15);
        int o = ((r << 7) + kb) ^ ((r & 7) << 4);
        bfr[n] = *(const bf16x8*)((const char*)Bs + o);
      }
#pragma unroll
      for (int m = 0; m < 4; ++m)
#pragma unroll
        for (int n = 0; n < 4; ++n)
          acc[m][n] = __builtin_amdgcn_mfma_f32_16x16x32_bf16(af[m], bfr[n], acc[m][n], 0, 0, 0);
    }
    __syncthreads();
  }
#pragma unroll
  for (int m = 0; m < 4; ++m) {
#pragma unroll
    for (int r = 0; r < 4; ++r) {
      int row = row0 + wr * 64 + m * 16 + ((lane >> 4) << 2) + r;
      int colb = col0 + wc * 64 + (lane & 15);
#pragma unroll
      for (int n = 0; n < 4; ++n) {
        float v = acc[m][n][r];
        if (F32OUT) ((float*)Cv)[(size_t)row * LDC + colb + n * 16] = v;
        else        ((u16*)Cv)[(size_t)row * LDC + colb + n * 16] = f2bf(v);
      }
    }
  }
}

// ---------------- flash attention (causal), Dh=64, QBLK=128 ----------------
// 512 uniform blocks: block handles (h,b) pair + strip pair {15-j, j} (34 tiles).
// XCD decode: all 8 blocks of an (h,b) on one XCD (KV slice ~0.5MB -> L2).
// 4 waves; wave w owns q-rows [q0+32w, q0+32w+32) as 2 frags of 16.
// K/V double-buffered; prefetch kt+1 before computing kt.
// lrow via MFMA row-sum (P x ones); defer-rescale THR=8; setprio on MFMA.
__global__ __launch_bounds__(256, 2)
void attn_fwd(const u16* __restrict__ Qg, const u16* __restrict__ Kg,
              const u16* __restrict__ VTg, u16* __restrict__ Og,
              int S, int H, int LDV) {
  __shared__ __align__(16) u16 Kb[2][64 * 64];   // [k][d], XOR-swizzled
  __shared__ __align__(16) u16 Vb[2][64 * 64];   // [d][k], XOR-swizzled
  __shared__ __align__(16) u16 Ps[4][16 * 64];   // per-wave P frag, XOR-swizzled
  const int tid = threadIdx.x, lane = tid & 63, wave = tid >> 6;
  const int xcd = blockIdx.x & 7, t = blockIdx.x >> 3;
  const int pair = xcd * 8 + (t >> 3);           // 64 (h,b) pairs, 8 per XCD
  const int j = t & 7;
  const int h = pair & 15, b = pair >> 4;
  const int D = H * 64;
  const int l15 = lane & 15, lg = lane >> 4;

  bf16x8 ones;
#pragma unroll
  for (int i = 0; i < 8; ++i) ones[i] = (__bf16)1.0f;

  for (int half = 0; half < 2; ++half) {
    const int qt = half ? j : (15 - j);
    const int q0 = qt * 128;
    const int wq0 = q0 + wave * 32;

    // Q fragments: qf[frag][dstep]
    bf16x8 qf[2][2];
#pragma unroll
    for (int f = 0; f < 2; ++f) {
      const u16* qp = Qg + (size_t)(b * S + wq0 + f * 16 + l15) * D + h * 64 + (lg << 3);
      qf[f][0] = *(const bf16x8*)qp;
      qf[f][1] = *(const bf16x8*)(qp + 32);
    }

    f32x4 accO[2][4] = {};
    float mrow[2][4], lrow[2][4];
#pragma unroll
    for (int f = 0; f < 2; ++f)
#pragma unroll
      for (int r = 0; r < 4; ++r) { mrow[f][r] = -__builtin_inff(); lrow[f][r] = 0.f; }

    const int nkt = 2 * qt + 2;

    auto STAGE = [&](int kt, int bufi) {
      const int k0 = kt * 64;
#pragma unroll
      for (int i = 0; i < 2; ++i) {
        int c = i * 256 + tid;
        int o = c << 4;
        int row = o >> 7;
        int ol = o ^ ((row & 7) << 4);
        int colel = (ol & 127) >> 1;
        int ldsoff = i * 4096 + wave * 1024;
        gld16(Kg + (size_t)(b * S + k0 + row) * D + h * 64 + colel,
              (char*)&Kb[bufi][0] + ldsoff);
        gld16(VTg + (size_t)(h * 64 + row) * LDV + b * S + k0 + colel,
              (char*)&Vb[bufi][0] + ldsoff);
      }
    };

    STAGE(0, 0);
    __syncthreads();

    for (int kt = 0; kt < nkt; ++kt) {
      const int cur = kt & 1;
      if (kt + 1 < nkt) STAGE(kt + 1, cur ^ 1);

      const int k0 = kt * 64;
      if (k0 <= wq0 + 31) {                      // wave has any unmasked col
        // ---- QK^T: sf[frag][kf], K frags shared across the two q-frags
        f32x4 sf[2][4] = {};
        __builtin_amdgcn_s_setprio(1);
#pragma unroll
        for (int dstep = 0; dstep < 2; ++dstep) {
          const int kb = dstep * 64 + (lg << 4);
#pragma unroll
          for (int kf = 0; kf < 4; ++kf) {
            int r = kf * 16 + l15;
            int o = ((r << 7) + kb) ^ ((r & 7) << 4);
            bf16x8 k8 = *(const bf16x8*)((const char*)&Kb[cur][0] + o);
            sf[0][kf] = __builtin_amdgcn_mfma_f32_16x16x32_bf16(qf[0][dstep], k8, sf[0][kf], 0, 0, 0);
            sf[1][kf] = __builtin_amdgcn_mfma_f32_16x16x32_bf16(qf[1][dstep], k8, sf[1][kf], 0, 0, 0);
          }
        }
        __builtin_amdgcn_s_setprio(0);

        const bool needmask = (k0 + 63 > wq0);
#pragma unroll
        for (int f = 0; f < 2; ++f) {
          // scale + causal mask + row max
          float rmax[4];
#pragma unroll
          for (int r = 0; r < 4; ++r) rmax[r] = -__builtin_inff();
          const int qbase = wq0 + f * 16 + (lg << 2);
#pragma unroll
          for (int kf = 0; kf < 4; ++kf) {
            int kcol = k0 + kf * 16 + l15;
#pragma unroll
            for (int r = 0; r < 4; ++r) {
              float s = sf[f][kf][r] * 0.125f;
              if (needmask && kcol > qbase + r) s = -__builtin_inff();
              sf[f][kf][r] = s;
              rmax[r] = fmaxf(rmax[r], s);
            }
          }
#pragma unroll
          for (int off = 1; off < 16; off <<= 1)
#pragma unroll
            for (int r = 0; r < 4; ++r)
              rmax[r] = fmaxf(rmax[r], __shfl_xor(rmax[r], off, 64));

          // defer-rescale (T13): only rescale when max grew by > 8
          float need = -__builtin_inff();
#pragma unroll
          for (int r = 0; r < 4; ++r) need = fmaxf(need, rmax[r] - mrow[f][r]);
          float scl[4];
          if (__any(need > 8.f)) {
#pragma unroll
            for (int r = 0; r < 4; ++r) {
              float mnew = fmaxf(mrow[f][r], rmax[r]);
              scl[r] = __expf(mrow[f][r] - mnew);
              mrow[f][r] = mnew;
            }
#pragma unroll
            for (int df = 0; df < 4; ++df)
#pragma unroll
              for (int r = 0; r < 4; ++r) accO[f][df][r] *= scl[r];
          } else {
#pragma unroll
            for (int r = 0; r < 4; ++r) scl[r] = 1.f;
          }

          // P = exp(s - m), store to per-wave LDS frag (swizzled)
#pragma unroll
          for (int kf = 0; kf < 4; ++kf) {
#pragma unroll
            for (int r = 0; r < 4; ++r) {
              float p = __expf(sf[f][kf][r] - mrow[f][r]);
              int prow = (lg << 2) + r;
              int pcol = kf * 16 + l15;
              int ob = ((prow << 7) + (pcol << 1)) ^ ((prow & 7) << 4);
              *(u16*)((char*)&Ps[wave][0] + ob) = f2bf(p);
            }
          }

          // ---- O += P V ; row-sum lsum = P x ones via MFMA (same-wave LDS, in-order)
          f32x4 ls = {};
          __builtin_amdgcn_s_setprio(1);
#pragma unroll
          for (int ks = 0; ks < 2; ++ks) {
            const int kb = ks * 64 + (lg << 4);
            int po = ((l15 << 7) + kb) ^ ((l15 & 7) << 4);
            bf16x8 pa = *(const bf16x8*)((const char*)&Ps[wave][0] + po);
            ls = __builtin_amdgcn_mfma_f32_16x16x32_bf16(pa, ones, ls, 0, 0, 0);
#pragma unroll
            for (int df = 0; df < 4; ++df) {
              int vr = df * 16 + l15;
              int vo = ((vr << 7) + kb) ^ ((vr & 7) << 4);
              bf16x8 v8 = *(const bf16x8*)((const char*)&Vb[cur][0] + vo);
              accO[f][df] = __builtin_amdgcn_mfma_f32_16x16x32_bf16(pa, v8, accO[f][df], 0, 0, 0);
            }
          }
          __builtin_amdgcn_s_setprio(0);
#pragma unroll
          for (int r = 0; r < 4; ++r) lrow[f][r] = lrow[f][r] * scl[r] + ls[r];
        }
      }
      __syncthreads();   // drains prefetch vmcnt + protects buffers
    }

    // write attn_out [b*S+q][h*64+d] bf16
#pragma unroll
    for (int f = 0; f < 2; ++f) {
#pragma unroll
      for (int df = 0; df < 4; ++df) {
#pragma unroll
        for (int r = 0; r < 4; ++r) {
          int row = wq0 + f * 16 + (lg << 2) + r;
          int col = h * 64 + df * 16 + l15;
          Og[(size_t)(b * S + row) * D + col] = f2bf(accO[f][df][r] / lrow[f][r]);
        }
      }
    }
    __syncthreads();   // strip boundary: all waves done with LDS before re-stage
  }
}

// ---------------- launch ----------------
extern "C" void kernel_launch(void* const* d_in, const int* in_sizes, int n_in,
                              void* d_out, int out_size, void* d_ws, size_t ws_size,
                              hipStream_t stream) {
  const float* residual = (const float*)d_in[0];
  const float* W_Q = (const float*)d_in[1];
  const float* W_K = (const float*)d_in[2];
  const float* W_V = (const float*)d_in[3];
  const float* W_O = (const float*)d_in[4];
  float* out = (float*)d_out;
  const int B = 4, S = 2048, D = 1024, H = 16;
  const int M = B * S;       // 8192
  const int LDV = M + 64;    // 8256: breaks power-of-2 set aliasing

  char* ws = (char*)d_ws;
  size_t off = 0;
  auto alloc = [&](size_t elems) {
    u16* p = (u16*)(ws + off);
    off += ((elems * 2 + 255) & ~(size_t)255);
    return p;
  };
  u16* resb = alloc((size_t)M * D);
  u16* Wqb  = alloc((size_t)D * D);
  u16* Wkb  = alloc((size_t)D * D);
  u16* Wvb  = alloc((size_t)D * D);
  u16* Wot  = alloc((size_t)D * D);
  u16* Qw   = alloc((size_t)M * D);
  u16* Kw   = alloc((size_t)M * D);
  u16* VT0  = alloc((size_t)D * LDV);  // V^T: [hd][b*S+s], padded row stride
  u16* AOw  = resb;  // residual-bf16 dead after QKV GEMMs — alias

  cast_f32_bf16<<<1024, 256, 0, stream>>>(residual, resb, M * D);
  cast_f32_bf16<<<256, 256, 0, stream>>>(W_Q, Wqb, D * D);
  cast_f32_bf16<<<256, 256, 0, stream>>>(W_K, Wkb, D * D);
  cast_f32_bf16<<<256, 256, 0, stream>>>(W_V, Wvb, D * D);
  transpose_cast<<<(D * D + 255) / 256, 256, 0, stream>>>(W_O, Wot, D, D);

  dim3 g(D / 128, M / 128);  // (8, 64)
  gemm_bt<0><<<g, 256, 0, stream>>>(resb, Wqb, Qw, M, D, D, D);
  gemm_bt<0><<<g, 256, 0, stream>>>(resb, Wkb, Kw, M, D, D, D);
  // V^T directly: VT0[hd][bs] = sum_m W_V[hd][m] * res[bs][m]
  dim3 gv(M / 128, D / 128);  // (64, 8)
  gemm_bt<0><<<gv, 256, 0, stream>>>(Wvb, resb, VT0, D, M, D, LDV);

  attn_fwd<<<dim3(512), 256, 0, stream>>>(Qw, Kw, VT0, AOw, S, H, LDV);

  gemm_bt<1><<<g, 256, 0, stream>>>(AOw, Wot, out, M, D, D, D);
}

// Round 9
// 291.377 us; speedup vs baseline: 1.8794x; 1.0524x over previous
//
#include <hip/hip_runtime.h>
#include <stdint.h>

typedef unsigned short u16;
typedef __bf16 bf16x8 __attribute__((ext_vector_type(8)));
typedef float f32x4 __attribute__((ext_vector_type(4)));
typedef short s16x8 __attribute__((ext_vector_type(8)));
typedef short s16x4 __attribute__((ext_vector_type(4)));

__device__ __forceinline__ u16 f2bf(float f) {
  unsigned u = __float_as_uint(f);
  u += 0x7fff + ((u >> 16) & 1);   // RNE
  return (u16)(u >> 16);
}

__device__ __forceinline__ void gld16(const void* g, void* l) {
  __builtin_amdgcn_global_load_lds((const __attribute__((address_space(1))) void*)g,
                                   (__attribute__((address_space(3))) void*)l, 16, 0, 0);
}

// ---------------- casts ----------------
__global__ void cast_f32_bf16(const float* __restrict__ in, u16* __restrict__ out, int n) {
  int stride = gridDim.x * blockDim.x;
  for (int i = blockIdx.x * blockDim.x + threadIdx.x; i * 4 < n; i += stride) {
    f32x4 v = *(const f32x4*)(in + (size_t)i * 4);
    s16x4 o;
#pragma unroll
    for (int j = 0; j < 4; ++j) o[j] = (short)f2bf(v[j]);
    *(s16x4*)(out + (size_t)i * 4) = o;
  }
}

// scaled variant (exact for power-of-2 scales: exponent shift, same bf16 rounding)
__global__ void cast_f32_bf16_scale(const float* __restrict__ in, u16* __restrict__ out,
                                    int n, float scale) {
  int stride = gridDim.x * blockDim.x;
  for (int i = blockIdx.x * blockDim.x + threadIdx.x; i * 4 < n; i += stride) {
    f32x4 v = *(const f32x4*)(in + (size_t)i * 4);
    s16x4 o;
#pragma unroll
    for (int j = 0; j < 4; ++j) o[j] = (short)f2bf(v[j] * scale);
    *(s16x4*)(out + (size_t)i * 4) = o;
  }
}

// W_O [hd][m] fp32 -> Wot [m][hd] bf16
__global__ void transpose_cast(const float* __restrict__ in, u16* __restrict__ out, int R, int C) {
  int idx = blockIdx.x * 256 + threadIdx.x;
  if (idx < R * C) {
    int r = idx / C, c = idx - r * C;
    out[(size_t)c * R + r] = f2bf(in[idx]);
  }
}

// ---------------- GEMM: C[M,N] = A[M,K] * B[N,K]^T (bf16 in, fp32 acc) ----------------
template<int F32OUT>
__global__ __launch_bounds__(256, 3)
void gemm_bt(const u16* __restrict__ A, const u16* __restrict__ B,
             void* __restrict__ Cv, int M, int N, int K, int LDC) {
  __shared__ __align__(16) u16 As[128 * 64];
  __shared__ __align__(16) u16 Bs[128 * 64];
  const int tid = threadIdx.x;
  const int lane = tid & 63;
  const int wave = tid >> 6;
  const int wr = wave >> 1, wc = wave & 1;
  const int row0 = blockIdx.y * 128, col0 = blockIdx.x * 128;
  const u16* Ab = A + (size_t)row0 * K;
  const u16* Bb = B + (size_t)col0 * K;
  f32x4 acc[4][4] = {};
  for (int kt = 0; kt < K; kt += 64) {
#pragma unroll
    for (int i = 0; i < 4; ++i) {
      int c = i * 256 + tid;
      int o = c << 4;
      int row = o >> 7;
      int ol = o ^ ((row & 7) << 4);
      int colel = (ol & 127) >> 1;
      int ldsoff = (i * 256 + wave * 64) << 4;
      gld16(Ab + (size_t)row * K + kt + colel, (char*)As + ldsoff);
      gld16(Bb + (size_t)row * K + kt + colel, (char*)Bs + ldsoff);
    }
    __syncthreads();
#pragma unroll
    for (int ks = 0; ks < 2; ++ks) {
      const int kb = ks * 64 + ((lane >> 4) << 4);
      bf16x8 af[4], bfr[4];
#pragma unroll
      for (int m = 0; m < 4; ++m) {
        int r = wr * 64 + m * 16 + (lane & 15);
        int o = ((r << 7) + kb) ^ ((r & 7) << 4);
        af[m] = *(const bf16x8*)((const char*)As + o);
      }
#pragma unroll
      for (int n = 0; n < 4; ++n) {
        int r = wc * 64 + n * 16 + (lane & 15);
        int o = ((r << 7) + kb) ^ ((r & 7) << 4);
        bfr[n] = *(const bf16x8*)((const char*)Bs + o);
      }
#pragma unroll
      for (int m = 0; m < 4; ++m)
#pragma unroll
        for (int n = 0; n < 4; ++n)
          acc[m][n] = __builtin_amdgcn_mfma_f32_16x16x32_bf16(af[m], bfr[n], acc[m][n], 0, 0, 0);
    }
    __syncthreads();
  }
#pragma unroll
  for (int m = 0; m < 4; ++m) {
#pragma unroll
    for (int r = 0; r < 4; ++r) {
      int row = row0 + wr * 64 + m * 16 + ((lane >> 4) << 2) + r;
      int colb = col0 + wc * 64 + (lane & 15);
#pragma unroll
      for (int n = 0; n < 4; ++n) {
        float v = acc[m][n][r];
        if (F32OUT) ((float*)Cv)[(size_t)row * LDC + colb + n * 16] = v;
        else        ((u16*)Cv)[(size_t)row * LDC + colb + n * 16] = f2bf(v);
      }
    }
  }
}

// ---------------- flash attention (causal), Dh=64, QBLK=128, 8 waves ----------------
// 512 uniform blocks x 512 threads: block = (h,b) pair + strip pair {15-j, j} (34 tiles).
// XCD decode: 8 blocks of an (h,b) on one XCD. Wave w owns q-rows [q0+16w, q0+16w+16).
// K/V double-buffered; prefetch kt+1 before computing kt. Q pre-scaled by 1/8 (W_Q cast).
// lrow via MFMA row-sum (P x ones); defer-rescale THR=8; setprio; uniform mask branch.
__global__ __launch_bounds__(512, 4)
void attn_fwd(const u16* __restrict__ Qg, const u16* __restrict__ Kg,
              const u16* __restrict__ VTg, u16* __restrict__ Og,
              int S, int H, int LDV) {
  __shared__ __align__(16) u16 Kb[2][64 * 64];   // [k][d], XOR-swizzled
  __shared__ __align__(16) u16 Vb[2][64 * 64];   // [d][k], XOR-swizzled
  __shared__ __align__(16) u16 Ps[8][16 * 64];   // per-wave P frag, XOR-swizzled
  const int tid = threadIdx.x, lane = tid & 63, wave = tid >> 6;  // wave 0..7
  const int xcd = blockIdx.x & 7, t = blockIdx.x >> 3;
  const int pair = xcd * 8 + (t >> 3);           // 64 (h,b) pairs, 8 per XCD
  const int j = t & 7;
  const int h = pair & 15, b = pair >> 4;
  const int D = H * 64;
  const int l15 = lane & 15, lg = lane >> 4;

  bf16x8 ones;
#pragma unroll
  for (int i = 0; i < 8; ++i) ones[i] = (__bf16)1.0f;

  for (int half = 0; half < 2; ++half) {
    const int qt = half ? j : (15 - j);
    const int q0 = qt * 128;
    const int wq0 = q0 + wave * 16;              // this wave's 16 q-rows

    const u16* qp = Qg + (size_t)(b * S + wq0 + l15) * D + h * 64 + (lg << 3);
    bf16x8 qf0 = *(const bf16x8*)qp;
    bf16x8 qf1 = *(const bf16x8*)(qp + 32);

    f32x4 accO[4] = {};
    float mrow[4], lrow[4];
#pragma unroll
    for (int r = 0; r < 4; ++r) { mrow[r] = -__builtin_inff(); lrow[r] = 0.f; }

    const int nkt = 2 * qt + 2;

    auto STAGE = [&](int kt, int bufi) {
      const int k0 = kt * 64;
      int o = tid << 4;                 // phys byte, 512 chunks x 16B = 8KB tile
      int row = o >> 7;                 // 128B per row
      int ol = o ^ ((row & 7) << 4);    // logical byte (involution)
      int colel = (ol & 127) >> 1;
      int ldsoff = wave << 10;          // wave-uniform base; lane x 16B fills linearly
      gld16(Kg + (size_t)(b * S + k0 + row) * D + h * 64 + colel,
            (char*)&Kb[bufi][0] + ldsoff);
      gld16(VTg + (size_t)(h * 64 + row) * LDV + b * S + k0 + colel,
            (char*)&Vb[bufi][0] + ldsoff);
    };

    STAGE(0, 0);
    __syncthreads();

    for (int kt = 0; kt < nkt; ++kt) {
      const int cur = kt & 1;
      if (kt + 1 < nkt) STAGE(kt + 1, cur ^ 1);

      const int k0 = kt * 64;
      if (k0 <= wq0 + 15) {                      // wave has any unmasked col
        // ---- QK^T (Q pre-scaled by 1/8)
        f32x4 sf[4] = {};
        __builtin_amdgcn_s_setprio(1);
#pragma unroll
        for (int dstep = 0; dstep < 2; ++dstep) {
          const int kb = dstep * 64 + (lg << 4);
          bf16x8 qa = dstep ? qf1 : qf0;
#pragma unroll
          for (int kf = 0; kf < 4; ++kf) {
            int r = kf * 16 + l15;
            int o = ((r << 7) + kb) ^ ((r & 7) << 4);
            bf16x8 k8 = *(const bf16x8*)((const char*)&Kb[cur][0] + o);
            sf[kf] = __builtin_amdgcn_mfma_f32_16x16x32_bf16(qa, k8, sf[kf], 0, 0, 0);
          }
        }
        __builtin_amdgcn_s_setprio(0);

        // causal mask (uniform branch: only ~1-2 diagonal tiles per strip) + row max
        float rmax[4];
#pragma unroll
        for (int r = 0; r < 4; ++r) rmax[r] = -__builtin_inff();
        const int qbase = wq0 + (lg << 2);
        if (k0 + 63 > wq0) {                     // diagonal tile: mask needed
#pragma unroll
          for (int kf = 0; kf < 4; ++kf) {
            int kcol = k0 + kf * 16 + l15;
#pragma unroll
            for (int r = 0; r < 4; ++r) {
              float s = sf[kf][r];
              if (kcol > qbase + r) s = -__builtin_inff();
              sf[kf][r] = s;
              rmax[r] = fmaxf(rmax[r], s);
            }
          }
        } else {
#pragma unroll
          for (int kf = 0; kf < 4; ++kf)
#pragma unroll
            for (int r = 0; r < 4; ++r) rmax[r] = fmaxf(rmax[r], sf[kf][r]);
        }
#pragma unroll
        for (int off = 1; off < 16; off <<= 1)
#pragma unroll
          for (int r = 0; r < 4; ++r)
            rmax[r] = fmaxf(rmax[r], __shfl_xor(rmax[r], off, 64));

        // defer-rescale (T13): only rescale when max grew by > 8
        float need = -__builtin_inff();
#pragma unroll
        for (int r = 0; r < 4; ++r) need = fmaxf(need, rmax[r] - mrow[r]);
        float scl[4];
        if (__any(need > 8.f)) {
#pragma unroll
          for (int r = 0; r < 4; ++r) {
            float mnew = fmaxf(mrow[r], rmax[r]);
            scl[r] = __expf(mrow[r] - mnew);
            mrow[r] = mnew;
          }
#pragma unroll
          for (int df = 0; df < 4; ++df)
#pragma unroll
            for (int r = 0; r < 4; ++r) accO[df][r] *= scl[r];
        } else {
#pragma unroll
          for (int r = 0; r < 4; ++r) scl[r] = 1.f;
        }

        // P = exp(s - m), store to per-wave LDS frag (swizzled)
#pragma unroll
        for (int kf = 0; kf < 4; ++kf) {
#pragma unroll
          for (int r = 0; r < 4; ++r) {
            float p = __expf(sf[kf][r] - mrow[r]);
            int prow = (lg << 2) + r;
            int pcol = kf * 16 + l15;
            int ob = ((prow << 7) + (pcol << 1)) ^ ((prow & 7) << 4);
            *(u16*)((char*)&Ps[wave][0] + ob) = f2bf(p);
          }
        }

        // ---- O += P V ; row-sum lsum = P x ones via MFMA (same-wave LDS, in-order)
        f32x4 ls = {};
        __builtin_amdgcn_s_setprio(1);
#pragma unroll
        for (int ks = 0; ks < 2; ++ks) {
          const int kb = ks * 64 + (lg << 4);
          int po = ((l15 << 7) + kb) ^ ((l15 & 7) << 4);
          bf16x8 pa = *(const bf16x8*)((const char*)&Ps[wave][0] + po);
          ls = __builtin_amdgcn_mfma_f32_16x16x32_bf16(pa, ones, ls, 0, 0, 0);
#pragma unroll
          for (int df = 0; df < 4; ++df) {
            int vr = df * 16 + l15;
            int vo = ((vr << 7) + kb) ^ ((vr & 7) << 4);
            bf16x8 v8 = *(const bf16x8*)((const char*)&Vb[cur][0] + vo);
            accO[df] = __builtin_amdgcn_mfma_f32_16x16x32_bf16(pa, v8, accO[df], 0, 0, 0);
          }
        }
        __builtin_amdgcn_s_setprio(0);
#pragma unroll
        for (int r = 0; r < 4; ++r) lrow[r] = lrow[r] * scl[r] + ls[r];
      }
      __syncthreads();   // drains prefetch vmcnt + protects buffers
    }

    // write attn_out [b*S+q][h*64+d] bf16
#pragma unroll
    for (int df = 0; df < 4; ++df) {
#pragma unroll
      for (int r = 0; r < 4; ++r) {
        int row = wq0 + (lg << 2) + r;
        int col = h * 64 + df * 16 + l15;
        Og[(size_t)(b * S + row) * D + col] = f2bf(accO[df][r] / lrow[r]);
      }
    }
    __syncthreads();   // strip boundary: all waves done with LDS before re-stage
  }
}

// ---------------- launch ----------------
extern "C" void kernel_launch(void* const* d_in, const int* in_sizes, int n_in,
                              void* d_out, int out_size, void* d_ws, size_t ws_size,
                              hipStream_t stream) {
  const float* residual = (const float*)d_in[0];
  const float* W_Q = (const float*)d_in[1];
  const float* W_K = (const float*)d_in[2];
  const float* W_V = (const float*)d_in[3];
  const float* W_O = (const float*)d_in[4];
  float* out = (float*)d_out;
  const int B = 4, S = 2048, D = 1024, H = 16;
  const int M = B * S;       // 8192
  const int LDV = M + 64;    // 8256: breaks power-of-2 set aliasing

  char* ws = (char*)d_ws;
  size_t off = 0;
  auto alloc = [&](size_t elems) {
    u16* p = (u16*)(ws + off);
    off += ((elems * 2 + 255) & ~(size_t)255);
    return p;
  };
  u16* resb = alloc((size_t)M * D);
  u16* Wqb  = alloc((size_t)D * D);
  u16* Wkb  = alloc((size_t)D * D);
  u16* Wvb  = alloc((size_t)D * D);
  u16* Wot  = alloc((size_t)D * D);
  u16* Qw   = alloc((size_t)M * D);
  u16* Kw   = alloc((size_t)M * D);
  u16* VT0  = alloc((size_t)D * LDV);  // V^T: [hd][b*S+s], padded row stride
  u16* AOw  = resb;  // residual-bf16 dead after QKV GEMMs — alias

  cast_f32_bf16<<<1024, 256, 0, stream>>>(residual, resb, M * D);
  // fold softmax 1/sqrt(64)=0.125 into W_Q (power-of-2: bit-exact vs scaling scores)
  cast_f32_bf16_scale<<<256, 256, 0, stream>>>(W_Q, Wqb, D * D, 0.125f);
  cast_f32_bf16<<<256, 256, 0, stream>>>(W_K, Wkb, D * D);
  cast_f32_bf16<<<256, 256, 0, stream>>>(W_V, Wvb, D * D);
  transpose_cast<<<(D * D + 255) / 256, 256, 0, stream>>>(W_O, Wot, D, D);

  dim3 g(D / 128, M / 128);  // (8, 64)
  gemm_bt<0><<<g, 256, 0, stream>>>(resb, Wqb, Qw, M, D, D, D);
  gemm_bt<0><<<g, 256, 0, stream>>>(resb, Wkb, Kw, M, D, D, D);
  // V^T directly: VT0[hd][bs] = sum_m W_V[hd][m] * res[bs][m]
  dim3 gv(M / 128, D / 128);  // (64, 8)
  gemm_bt<0><<<gv, 256, 0, stream>>>(Wvb, resb, VT0, D, M, D, LDV);

  attn_fwd<<<dim3(512), 512, 0, stream>>>(Qw, Kw, VT0, AOw, S, H, LDV);

  gemm_bt<1><<<g, 256, 0, stream>>>(AOw, Wot, out, M, D, D, D);
}